// Round 4
// baseline (452.809 us; speedup 1.0000x reference)
//
#include <hip/hip_runtime.h>

typedef __attribute__((ext_vector_type(4))) float f32x4;
typedef __attribute__((ext_vector_type(8))) short short8;
typedef __attribute__((ext_vector_type(4))) unsigned short us4;
typedef __attribute__((ext_vector_type(8))) unsigned short us8;

// problem constants
#define D_MODEL 256
#define SEQ 8192L
#define NBATCH 8
#define TOTROWS 65536L   // NBATCH * SEQ

__device__ inline unsigned short f2bf(float f){
  unsigned int u = __float_as_uint(f);
  u += 0x7fffu + ((u >> 16) & 1u);      // RNE
  return (unsigned short)(u >> 16);
}
__device__ inline float bf2f(unsigned short h){
  return __uint_as_float(((unsigned int)h) << 16);
}
__device__ inline f32x4 mfma16(short8 a, short8 b, f32x4 c){
  return __builtin_amdgcn_mfma_f32_16x16x32_bf16(a, b, c, 0, 0, 0);
}
__device__ inline us8 pack8(f32x4 a, f32x4 b){
  us8 o;
  o[0]=f2bf(a[0]); o[1]=f2bf(a[1]); o[2]=f2bf(a[2]); o[3]=f2bf(a[3]);
  o[4]=f2bf(b[0]); o[5]=f2bf(b[1]); o[6]=f2bf(b[2]); o[7]=f2bf(b[3]);
  return o;
}

// ---------------------------------------------------------------------------
// prep: WT[m][n][k] = W_m[k][n] as bf16.  slots: 0 Wq, 1 Wk, 2 Wv, 3 Wm,
//       4 W1a(=W1[0:256]), 5 W1b(=W1[256:512]), 6 W2
// ---------------------------------------------------------------------------
__global__ void prep_weights(const float* __restrict__ Wq, const float* __restrict__ Wk,
                             const float* __restrict__ Wv, const float* __restrict__ Wm,
                             const float* __restrict__ W1, const float* __restrict__ W2,
                             unsigned short* __restrict__ WT){
  int o = blockIdx.x * 256 + threadIdx.x;           // 7*65536 total
  int m = o >> 16, rem = o & 65535, n = rem >> 8, k = rem & 255;
  const float* s;
  switch(m){
    case 0: s = Wq; break;
    case 1: s = Wk; break;
    case 2: s = Wv; break;
    case 3: s = Wm; break;
    case 4: s = W1; break;
    case 5: s = W1 + 65536; break;
    default: s = W2; break;
  }
  WT[o] = f2bf(s[k * 256 + n]);
}

// ---------------------------------------------------------------------------
// kv_proj: [Kw|Vw] = source @ [Wk|Wv], epilogue elu+1 (K) or *1/S (V), bf16 out
// grid (512 mblocks, 4 nblocks), 256 thr.  BM=128, BN=128, BK=32, waves 2x2.
// ---------------------------------------------------------------------------
__global__ __launch_bounds__(256) void kv_proj(
    const float* __restrict__ src, const unsigned short* __restrict__ WT,
    unsigned short* __restrict__ Kw, unsigned short* __restrict__ Vw)
{
  __shared__ unsigned short As[128][40];
  __shared__ unsigned short Bs[128][40];
  const int t = threadIdx.x, lane = t & 63, wid = t >> 6;
  const int l16 = lane & 15, g4 = lane >> 4;
  const int wr = (wid >> 1) * 64, wc = (wid & 1) * 64;
  const int mb = blockIdx.x, nb = blockIdx.y;
  const long rowbase = (long)mb * 128;
  const unsigned short* Wsl = WT + (nb < 2 ? 1 : 2) * 65536 + (nb & 1) * 128 * 256;
  const int rA = t >> 1, cA = (t & 1) * 16;

  f32x4 acc[4][4] = {};
  for(int kb = 0; kb < 256; kb += 32){
    {
      const float* g = src + (rowbase + rA) * 256 + kb + cA;
      f32x4 v0 = *(const f32x4*)g;
      f32x4 v1 = *(const f32x4*)(g + 4);
      f32x4 v2 = *(const f32x4*)(g + 8);
      f32x4 v3 = *(const f32x4*)(g + 12);
      *(us8*)&As[rA][cA]     = pack8(v0, v1);
      *(us8*)&As[rA][cA + 8] = pack8(v2, v3);
      const unsigned short* wb = Wsl + rA * 256 + kb + cA;
      *(us8*)&Bs[rA][cA]     = *(const us8*)wb;
      *(us8*)&Bs[rA][cA + 8] = *(const us8*)(wb + 8);
    }
    __syncthreads();
    short8 afr[4], bfr[4];
    #pragma unroll
    for(int mi = 0; mi < 4; mi++) afr[mi] = *(const short8*)&As[wr + mi*16 + l16][g4*8];
    #pragma unroll
    for(int ni = 0; ni < 4; ni++) bfr[ni] = *(const short8*)&Bs[wc + ni*16 + l16][g4*8];
    #pragma unroll
    for(int mi = 0; mi < 4; mi++)
      #pragma unroll
      for(int ni = 0; ni < 4; ni++)
        acc[mi][ni] = mfma16(afr[mi], bfr[ni], acc[mi][ni]);
    __syncthreads();
  }

  const bool isK = nb < 2;
  unsigned short* dst = isK ? Kw : Vw;
  const int colbase = (nb & 1) * 128 + wc;
  #pragma unroll
  for(int mi = 0; mi < 4; mi++)
    #pragma unroll
    for(int ni = 0; ni < 4; ni++)
      #pragma unroll
      for(int rr = 0; rr < 4; rr++){
        long row = rowbase + wr + mi*16 + g4*4 + rr;
        int col = colbase + ni*16 + l16;
        float v = acc[mi][ni][rr];
        v = isK ? (v > 0.f ? v + 1.f : __expf(v)) : v * (1.f / 8192.f);
        dst[row * 256 + col] = f2bf(v);
      }
}

// ---------------------------------------------------------------------------
// kv_acc: per (n, 128-row chunk): partial KV[h][d][v] and Ksum[h][d].
// thread t -> (h=t>>5, d=t&31), acc[v] in regs.  part layout [n][c][v(33)][t]
// ---------------------------------------------------------------------------
__global__ __launch_bounds__(256) void kv_acc(const unsigned short* __restrict__ Kw,
                                              const unsigned short* __restrict__ Vw,
                                              float* __restrict__ part){
  const int c = blockIdx.x;      // 0..63
  const int n = blockIdx.y;      // 0..7
  const int t = threadIdx.x;
  const int h = t >> 5, d = t & 31;
  const long base = ((long)n * SEQ + (long)c * 128) * 256;
  float acc[32];
  #pragma unroll
  for(int j = 0; j < 32; j++) acc[j] = 0.f;
  float ks = 0.f;
  for(int rr = 0; rr < 128; rr++){
    const unsigned short* Kr = Kw + base + (long)rr * 256;
    const unsigned short* Vr = Vw + base + (long)rr * 256;
    float kv = bf2f(Kr[h * 32 + d]);
    ks += kv;
    #pragma unroll
    for(int q = 0; q < 4; q++){
      us8 vv = *(const us8*)(Vr + h * 32 + q * 8);
      #pragma unroll
      for(int j = 0; j < 8; j++) acc[q*8 + j] += kv * bf2f(vv[j]);
    }
  }
  float* p = part + ((long)(n * 64 + c) * 33) * 256;
  #pragma unroll
  for(int v = 0; v < 32; v++) p[v * 256 + t] = acc[v];
  p[32 * 256 + t] = ks;
}

// ---------------------------------------------------------------------------
// kv_red: KVws[n][v(33)][t] = sum_c part[n][c][v][t]   (v==32 is Ksum)
// ---------------------------------------------------------------------------
__global__ void kv_red(const float* __restrict__ part, float* __restrict__ KVws){
  const int v = blockIdx.x;   // 0..32
  const int n = blockIdx.y;   // 0..7
  const int t = threadIdx.x;
  float s = 0.f;
  for(int c = 0; c < 64; c++) s += part[((long)(n * 64 + c) * 33 + v) * 256 + t];
  KVws[((long)n * 33 + v) * 256 + t] = s;
}

// ---------------------------------------------------------------------------
// attn: q=x@Wq -> elu+1 -> att = (Q@KV)*z*S -> msg=att@Wm -> LN1 -> msgln(bf16)
// grid 1024 (BM=64, BN=256), 256 thr (4 waves, 1x4).
// ---------------------------------------------------------------------------
__global__ __launch_bounds__(256) void attn_kern(
    const float* __restrict__ x, const unsigned short* __restrict__ WT,
    const float* __restrict__ KVws, const float* __restrict__ g1,
    const float* __restrict__ b1, unsigned short* __restrict__ msgln)
{
  __shared__ unsigned short As[64][40];     //  5120 B
  __shared__ unsigned short Bu[256][40];    // 20480 B (Wq/Wm chunks, then kvT)
  __shared__ float zs[64][8];               //  2048 B
  __shared__ float ksl[256];                //  1024 B
  __shared__ unsigned short R[64][264];     // 33792 B (Q -> att -> msg)

  const int t = threadIdx.x, lane = t & 63, wid = t >> 6;
  const int l16 = lane & 15, g4 = lane >> 4;
  const int wc = wid * 64;
  const int mb = blockIdx.x;
  const long rowbase = (long)mb * 64;
  const int n = mb >> 7;                    // batch
  const int rS = t >> 2, cS = (t & 3) * 8;  // A-staging map

  // phase 1: q = x @ Wq
  f32x4 acc[4][4] = {};
  {
    const unsigned short* wq = WT;          // slot 0
    for(int kb = 0; kb < 256; kb += 32){
      const float* g = x + (rowbase + rS) * 256 + kb + cS;
      f32x4 v0 = *(const f32x4*)g;
      f32x4 v1 = *(const f32x4*)(g + 4);
      *(us8*)&As[rS][cS] = pack8(v0, v1);
      const unsigned short* wb = wq + t * 256 + kb;
      *(us8*)&Bu[t][0]  = *(const us8*)(wb);
      *(us8*)&Bu[t][8]  = *(const us8*)(wb + 8);
      *(us8*)&Bu[t][16] = *(const us8*)(wb + 16);
      *(us8*)&Bu[t][24] = *(const us8*)(wb + 24);
      __syncthreads();
      short8 afr[4], bfr[4];
      #pragma unroll
      for(int mi = 0; mi < 4; mi++) afr[mi] = *(const short8*)&As[mi*16 + l16][g4*8];
      #pragma unroll
      for(int ni = 0; ni < 4; ni++) bfr[ni] = *(const short8*)&Bu[wc + ni*16 + l16][g4*8];
      #pragma unroll
      for(int mi = 0; mi < 4; mi++)
        #pragma unroll
        for(int ni = 0; ni < 4; ni++)
          acc[mi][ni] = mfma16(afr[mi], bfr[ni], acc[mi][ni]);
      __syncthreads();
    }
  }

  // phase 2: Q = elu(q)+1 -> R (bf16)
  #pragma unroll
  for(int mi = 0; mi < 4; mi++)
    #pragma unroll
    for(int ni = 0; ni < 4; ni++)
      #pragma unroll
      for(int rr = 0; rr < 4; rr++){
        float v = acc[mi][ni][rr];
        v = v > 0.f ? v + 1.f : __expf(v);
        R[mi*16 + g4*4 + rr][wc + ni*16 + l16] = f2bf(v);
      }

  // phase 3: stage kvT (Bu[c=h*32+v][d]) and Ksum
  {
    const float* kvn = KVws + (long)n * 33 * 256;
    const int vv = t & 31, hh = t >> 5;
    #pragma unroll
    for(int d = 0; d < 32; d += 4){
      f32x4 w = *(const f32x4*)(kvn + vv * 256 + hh * 32 + d);
      us4 o; o[0]=f2bf(w[0]); o[1]=f2bf(w[1]); o[2]=f2bf(w[2]); o[3]=f2bf(w[3]);
      *(us4*)&Bu[t][d] = o;
    }
    ksl[t] = kvn[32 * 256 + t];
  }
  __syncthreads();

  // phase 4: z[row][h] = 1/(Q.Ksum + eps)
  #pragma unroll
  for(int pp = 0; pp < 2; pp++){
    int p = t + pp * 256;
    int row = p >> 3, h = p & 7;
    float s = 0.f;
    #pragma unroll
    for(int d = 0; d < 32; d++) s += bf2f(R[row][h*32 + d]) * ksl[h*32 + d];
    zs[row][h] = 1.f / (s + 1e-6f);
  }
  __syncthreads();

  // phase 5: att = (Q @ KV) * z * S
  f32x4 acc2[4][4];
  #pragma unroll
  for(int ni = 0; ni < 4; ni++){
    const int cb = wc + ni * 16;
    const int h = cb >> 5;
    short8 b = *(const short8*)&Bu[cb + l16][g4*8];
    #pragma unroll
    for(int mi = 0; mi < 4; mi++){
      short8 a = *(const short8*)&R[mi*16 + l16][h*32 + g4*8];
      f32x4 zz = {0.f, 0.f, 0.f, 0.f};
      acc2[mi][ni] = mfma16(a, b, zz);
    }
  }
  #pragma unroll
  for(int mi = 0; mi < 4; mi++)
    #pragma unroll
    for(int ni = 0; ni < 4; ni++){
      const int h = (wc + ni * 16) >> 5;
      #pragma unroll
      for(int rr = 0; rr < 4; rr++){
        int row = mi*16 + g4*4 + rr;
        acc2[mi][ni][rr] *= zs[row][h] * 8192.f;
      }
    }
  __syncthreads();   // all R reads done
  #pragma unroll
  for(int mi = 0; mi < 4; mi++)
    #pragma unroll
    for(int ni = 0; ni < 4; ni++)
      #pragma unroll
      for(int rr = 0; rr < 4; rr++)
        R[mi*16 + g4*4 + rr][wc + ni*16 + l16] = f2bf(acc2[mi][ni][rr]);
  __syncthreads();

  // phase 6: msg = att @ Wm
  f32x4 acc3[4][4] = {};
  {
    const unsigned short* wm = WT + 3 * 65536;
    for(int kb = 0; kb < 256; kb += 32){
      const unsigned short* wb = wm + t * 256 + kb;
      *(us8*)&Bu[t][0]  = *(const us8*)(wb);
      *(us8*)&Bu[t][8]  = *(const us8*)(wb + 8);
      *(us8*)&Bu[t][16] = *(const us8*)(wb + 16);
      *(us8*)&Bu[t][24] = *(const us8*)(wb + 24);
      __syncthreads();
      short8 afr[4], bfr[4];
      #pragma unroll
      for(int mi = 0; mi < 4; mi++) afr[mi] = *(const short8*)&R[mi*16 + l16][kb + g4*8];
      #pragma unroll
      for(int ni = 0; ni < 4; ni++) bfr[ni] = *(const short8*)&Bu[wc + ni*16 + l16][g4*8];
      #pragma unroll
      for(int mi = 0; mi < 4; mi++)
        #pragma unroll
        for(int ni = 0; ni < 4; ni++)
          acc3[mi][ni] = mfma16(afr[mi], bfr[ni], acc3[mi][ni]);
      __syncthreads();
    }
  }

  // phase 7: msg -> R
  #pragma unroll
  for(int mi = 0; mi < 4; mi++)
    #pragma unroll
    for(int ni = 0; ni < 4; ni++)
      #pragma unroll
      for(int rr = 0; rr < 4; rr++)
        R[mi*16 + g4*4 + rr][wc + ni*16 + l16] = f2bf(acc3[mi][ni][rr]);
  __syncthreads();

  // phase 8: LN1 + store msgln
  {
    int row = t >> 2, q = t & 3;
    float s = 0.f, ss = 0.f;
    #pragma unroll
    for(int j8 = 0; j8 < 8; j8++){
      us8 vv = *(const us8*)&R[row][q*64 + j8*8];
      #pragma unroll
      for(int e = 0; e < 8; e++){ float v = bf2f(vv[e]); s += v; ss += v * v; }
    }
    s  += __shfl_xor(s, 1);  ss += __shfl_xor(ss, 1);
    s  += __shfl_xor(s, 2);  ss += __shfl_xor(ss, 2);
    float mu  = s * (1.f / 256.f);
    float var = ss * (1.f / 256.f) - mu * mu;
    float rs  = rsqrtf(var + 1e-5f);
    unsigned short* orow = msgln + (rowbase + row) * 256 + q * 64;
    const float* g1p = g1 + q * 64;
    const float* b1p = b1 + q * 64;
    #pragma unroll
    for(int j8 = 0; j8 < 8; j8++){
      us8 vv = *(const us8*)&R[row][q*64 + j8*8];
      us8 o;
      #pragma unroll
      for(int e = 0; e < 8; e++){
        float v = (bf2f(vv[e]) - mu) * rs * g1p[j8*8 + e] + b1p[j8*8 + e];
        o[e] = f2bf(v);
      }
      *(us8*)(orow + j8*8) = o;
    }
  }
}

// ---------------------------------------------------------------------------
// ffn: h = relu(x@W1a + msgln@W1b); y = h@W2; out = x + LN2(y)
// grid 1024 (BM=64, BN=256), 256 thr.
// ---------------------------------------------------------------------------
__global__ __launch_bounds__(256) void ffn_kern(
    const float* __restrict__ x, const unsigned short* __restrict__ WT,
    const unsigned short* __restrict__ msgln, const float* __restrict__ g2,
    const float* __restrict__ b2, float* __restrict__ out)
{
  __shared__ unsigned short As[64][40];
  __shared__ unsigned short Bs[256][40];
  __shared__ unsigned short R[64][264];
  const int t = threadIdx.x, lane = t & 63, wid = t >> 6;
  const int l16 = lane & 15, g4 = lane >> 4;
  const int wc = wid * 64;
  const long rowbase = (long)blockIdx.x * 64;
  const int rS = t >> 2, cS = (t & 3) * 8;

  // phase 1: h = x@W1a + msgln@W1b  (K_eff = 512)
  f32x4 acc[4][4] = {};
  for(int it = 0; it < 16; it++){
    int kb = it * 32;
    if(it < 8){
      const float* g = x + (rowbase + rS) * 256 + kb + cS;
      f32x4 v0 = *(const f32x4*)g;
      f32x4 v1 = *(const f32x4*)(g + 4);
      *(us8*)&As[rS][cS] = pack8(v0, v1);
    } else {
      const unsigned short* g = msgln + (rowbase + rS) * 256 + (kb & 255) + cS;
      *(us8*)&As[rS][cS] = *(const us8*)g;
    }
    const unsigned short* wsl = WT + (it < 8 ? 4 : 5) * 65536 + t * 256 + (kb & 255);
    *(us8*)&Bs[t][0]  = *(const us8*)(wsl);
    *(us8*)&Bs[t][8]  = *(const us8*)(wsl + 8);
    *(us8*)&Bs[t][16] = *(const us8*)(wsl + 16);
    *(us8*)&Bs[t][24] = *(const us8*)(wsl + 24);
    __syncthreads();
    short8 afr[4], bfr[4];
    #pragma unroll
    for(int mi = 0; mi < 4; mi++) afr[mi] = *(const short8*)&As[mi*16 + l16][g4*8];
    #pragma unroll
    for(int ni = 0; ni < 4; ni++) bfr[ni] = *(const short8*)&Bs[wc + ni*16 + l16][g4*8];
    #pragma unroll
    for(int mi = 0; mi < 4; mi++)
      #pragma unroll
      for(int ni = 0; ni < 4; ni++)
        acc[mi][ni] = mfma16(afr[mi], bfr[ni], acc[mi][ni]);
    __syncthreads();
  }

  // relu -> R
  #pragma unroll
  for(int mi = 0; mi < 4; mi++)
    #pragma unroll
    for(int ni = 0; ni < 4; ni++)
      #pragma unroll
      for(int rr = 0; rr < 4; rr++){
        float v = acc[mi][ni][rr];
        R[mi*16 + g4*4 + rr][wc + ni*16 + l16] = f2bf(v > 0.f ? v : 0.f);
      }
  __syncthreads();

  // phase 2: y = h @ W2
  f32x4 acc2[4][4] = {};
  {
    const unsigned short* w2 = WT + 6 * 65536;
    for(int kb = 0; kb < 256; kb += 32){
      const unsigned short* wb = w2 + t * 256 + kb;
      *(us8*)&Bs[t][0]  = *(const us8*)(wb);
      *(us8*)&Bs[t][8]  = *(const us8*)(wb + 8);
      *(us8*)&Bs[t][16] = *(const us8*)(wb + 16);
      *(us8*)&Bs[t][24] = *(const us8*)(wb + 24);
      __syncthreads();
      short8 afr[4], bfr[4];
      #pragma unroll
      for(int mi = 0; mi < 4; mi++) afr[mi] = *(const short8*)&R[mi*16 + l16][kb + g4*8];
      #pragma unroll
      for(int ni = 0; ni < 4; ni++) bfr[ni] = *(const short8*)&Bs[wc + ni*16 + l16][g4*8];
      #pragma unroll
      for(int mi = 0; mi < 4; mi++)
        #pragma unroll
        for(int ni = 0; ni < 4; ni++)
          acc2[mi][ni] = mfma16(afr[mi], bfr[ni], acc2[mi][ni]);
      __syncthreads();
    }
  }

  // y -> R
  #pragma unroll
  for(int mi = 0; mi < 4; mi++)
    #pragma unroll
    for(int ni = 0; ni < 4; ni++)
      #pragma unroll
      for(int rr = 0; rr < 4; rr++)
        R[mi*16 + g4*4 + rr][wc + ni*16 + l16] = f2bf(acc2[mi][ni][rr]);
  __syncthreads();

  // LN2 + residual + store
  {
    int row = t >> 2, q = t & 3;
    float s = 0.f, ss = 0.f;
    #pragma unroll
    for(int j8 = 0; j8 < 8; j8++){
      us8 vv = *(const us8*)&R[row][q*64 + j8*8];
      #pragma unroll
      for(int e = 0; e < 8; e++){ float v = bf2f(vv[e]); s += v; ss += v * v; }
    }
    s  += __shfl_xor(s, 1);  ss += __shfl_xor(ss, 1);
    s  += __shfl_xor(s, 2);  ss += __shfl_xor(ss, 2);
    float mu  = s * (1.f / 256.f);
    float var = ss * (1.f / 256.f) - mu * mu;
    float rs  = rsqrtf(var + 1e-5f);
    const float* xr = x + (rowbase + row) * 256 + q * 64;
    float* orow = out + (rowbase + row) * 256 + q * 64;
    const float* g2p = g2 + q * 64;
    const float* b2p = b2 + q * 64;
    #pragma unroll
    for(int j4 = 0; j4 < 16; j4++){
      f32x4 xv = *(const f32x4*)(xr + j4 * 4);
      f32x4 o;
      #pragma unroll
      for(int e = 0; e < 4; e++){
        int idx = j4 * 4 + e;
        float v = (bf2f(R[row][q*64 + idx]) - mu) * rs * g2p[idx] + b2p[idx];
        o[e] = xv[e] + v;
      }
      *(f32x4*)(orow + j4 * 4) = o;
    }
  }
}

// ---------------------------------------------------------------------------
extern "C" void kernel_launch(void* const* d_in, const int* in_sizes, int n_in,
                              void* d_out, int out_size, void* d_ws, size_t ws_size,
                              hipStream_t stream)
{
  const float* x   = (const float*)d_in[0];
  const float* src = (const float*)d_in[1];
  const float* Wq  = (const float*)d_in[2];
  const float* Wk  = (const float*)d_in[3];
  const float* Wv  = (const float*)d_in[4];
  const float* Wm  = (const float*)d_in[5];
  const float* W1  = (const float*)d_in[6];
  const float* W2  = (const float*)d_in[7];
  const float* g1  = (const float*)d_in[8];
  const float* b1  = (const float*)d_in[9];
  const float* g2  = (const float*)d_in[10];
  const float* b2  = (const float*)d_in[11];

  char* ws = (char*)d_ws;
  // ws layout (bytes):
  //   [0,        1 MB)      WT   : 7 x 256 x 256 bf16 (917504 B)
  //   [1 MB,    +32 MB)     Kw   : 65536 x 256 bf16   (dead after kv_acc)
  //                          msgln aliases Kw (live from attn_kern on)
  //   [+32 MB,  +32 MB)     Vw
  //   [+32 MB,  +16.5 MB)   part : 512 x 33 x 256 f32
  //   [...,     +270336 B)  KVws : 8 x 33 x 256 f32
  // total ~82 MB
  unsigned short* WT   = (unsigned short*)(ws);
  unsigned short* Kw   = (unsigned short*)(ws + (1ul << 20));
  unsigned short* msgl = Kw;   // alias: Kw dead before attn_kern writes msgln
  unsigned short* Vw   = (unsigned short*)(ws + (1ul << 20) + 33554432ul);
  float* part          = (float*)(ws + (1ul << 20) + 2ul * 33554432ul);
  float* KVws          = (float*)(ws + (1ul << 20) + 2ul * 33554432ul + 17301504ul);

  prep_weights<<<1792, 256, 0, stream>>>(Wq, Wk, Wv, Wm, W1, W2, WT);
  kv_proj<<<dim3(512, 4), 256, 0, stream>>>(src, WT, Kw, Vw);
  kv_acc<<<dim3(64, 8), 256, 0, stream>>>(Kw, Vw, part);
  kv_red<<<dim3(33, 8), 256, 0, stream>>>(part, KVws);
  attn_kern<<<1024, 256, 0, stream>>>(x, WT, KVws, g1, b1, msgl);
  ffn_kern<<<1024, 256, 0, stream>>>(x, WT, msgl, g2, b2, (float*)d_out);
}

// Round 7
// 415.757 us; speedup vs baseline: 1.0891x; 1.0891x over previous
//
#include <hip/hip_runtime.h>

typedef __attribute__((ext_vector_type(4))) float f32x4;
typedef __attribute__((ext_vector_type(8))) short short8;
typedef __attribute__((ext_vector_type(4))) unsigned short us4;
typedef __attribute__((ext_vector_type(8))) unsigned short us8;

// problem constants
#define D_MODEL 256
#define SEQ 8192L
#define NBATCH 8
#define TOTROWS 65536L   // NBATCH * SEQ

__device__ inline unsigned short f2bf(float f){
  unsigned int u = __float_as_uint(f);
  u += 0x7fffu + ((u >> 16) & 1u);      // RNE
  return (unsigned short)(u >> 16);
}
__device__ inline float bf2f(unsigned short h){
  return __uint_as_float(((unsigned int)h) << 16);
}
__device__ inline f32x4 mfma16(short8 a, short8 b, f32x4 c){
  return __builtin_amdgcn_mfma_f32_16x16x32_bf16(a, b, c, 0, 0, 0);
}
__device__ inline us8 pack8(f32x4 a, f32x4 b){
  us8 o;
  o[0]=f2bf(a[0]); o[1]=f2bf(a[1]); o[2]=f2bf(a[2]); o[3]=f2bf(a[3]);
  o[4]=f2bf(b[0]); o[5]=f2bf(b[1]); o[6]=f2bf(b[2]); o[7]=f2bf(b[3]);
  return o;
}
// async global->LDS, 16B per lane; dest = wave-uniform base + lane*16
__device__ inline void gl16(const unsigned short* g, unsigned short* lds){
  __builtin_amdgcn_global_load_lds(
      (const __attribute__((address_space(1))) unsigned int*)g,
      (__attribute__((address_space(3))) unsigned int*)lds, 16, 0, 0);
}

// ---------------------------------------------------------------------------
// conv_f32_to_bf16: d = bf16(s), 8 elems per thread-chunk, grid-stride.
// ---------------------------------------------------------------------------
__global__ __launch_bounds__(256) void conv_f32_to_bf16(
    const float* __restrict__ s, unsigned short* __restrict__ d){
  const long N = TOTROWS * 256 / 8;          // chunks
  for(long c = (long)blockIdx.x * 256 + threadIdx.x; c < N;
      c += (long)gridDim.x * 256){
    long off = c * 8;
    f32x4 v0 = *(const f32x4*)(s + off);
    f32x4 v1 = *(const f32x4*)(s + off + 4);
    *(us8*)(d + off) = pack8(v0, v1);
  }
}

// ---------------------------------------------------------------------------
// prep: WT[m][n][k] = W_m[k][n] as bf16.  slots: 0 Wq, 1 Wk, 2 Wv, 3 Wm,
//       4 W1a(=W1[0:256]), 5 W1b(=W1[256:512]), 6 W2
// ---------------------------------------------------------------------------
__global__ void prep_weights(const float* __restrict__ Wq, const float* __restrict__ Wk,
                             const float* __restrict__ Wv, const float* __restrict__ Wm,
                             const float* __restrict__ W1, const float* __restrict__ W2,
                             unsigned short* __restrict__ WT){
  int o = blockIdx.x * 256 + threadIdx.x;           // 7*65536 total
  int m = o >> 16, rem = o & 65535, n = rem >> 8, k = rem & 255;
  const float* s;
  switch(m){
    case 0: s = Wq; break;
    case 1: s = Wk; break;
    case 2: s = Wv; break;
    case 3: s = Wm; break;
    case 4: s = W1; break;
    case 5: s = W1 + 65536; break;
    default: s = W2; break;
  }
  WT[o] = f2bf(s[k * 256 + n]);
}

// ---------------------------------------------------------------------------
// kv_proj: [Kw|Vw] = srcb @ [Wk|Wv], epilogue elu+1 (K) or *1/S (V), bf16 out
// grid (512, 4), 256 thr.  BM=128, BN=128, BK=32, waves 2x2.  LDS 16 KB.
// ---------------------------------------------------------------------------
__global__ __launch_bounds__(256) void kv_proj(
    const unsigned short* __restrict__ srcb, const unsigned short* __restrict__ WT,
    unsigned short* __restrict__ Kw, unsigned short* __restrict__ Vw)
{
  __shared__ unsigned short As[128][32];
  __shared__ unsigned short Bs[128][32];
  const int t = threadIdx.x, lane = t & 63, wid = t >> 6;
  const int l16 = lane & 15, g4 = lane >> 4;
  const int wr = (wid >> 1) * 64, wc = (wid & 1) * 64;
  const int mb = blockIdx.x, nb = blockIdx.y;
  const long rowbase = (long)mb * 128;
  const unsigned short* Wsl = WT + (nb < 2 ? 1 : 2) * 65536 + (nb & 1) * 128 * 256;
  const int sr = lane >> 2, sc = (lane & 3) * 8;    // staging map: 16 rows x 4 chunks

  f32x4 acc[4][4] = {};
  for(int kb = 0; kb < 256; kb += 32){
    #pragma unroll
    for(int j = 0; j < 2; j++){
      int r0 = wid * 32 + j * 16;
      gl16(srcb + (rowbase + r0 + sr) * 256 + kb + sc, &As[r0][0]);
      gl16(Wsl  + (long)(r0 + sr) * 256 + kb + sc,     &Bs[r0][0]);
    }
    __syncthreads();
    short8 afr[4], bfr[4];
    #pragma unroll
    for(int mi = 0; mi < 4; mi++) afr[mi] = *(const short8*)&As[wr + mi*16 + l16][g4*8];
    #pragma unroll
    for(int ni = 0; ni < 4; ni++) bfr[ni] = *(const short8*)&Bs[wc + ni*16 + l16][g4*8];
    #pragma unroll
    for(int mi = 0; mi < 4; mi++)
      #pragma unroll
      for(int ni = 0; ni < 4; ni++)
        acc[mi][ni] = mfma16(afr[mi], bfr[ni], acc[mi][ni]);
    __syncthreads();
  }

  const bool isK = nb < 2;
  unsigned short* dst = isK ? Kw : Vw;
  const int colbase = (nb & 1) * 128 + wc;
  #pragma unroll
  for(int mi = 0; mi < 4; mi++)
    #pragma unroll
    for(int ni = 0; ni < 4; ni++)
      #pragma unroll
      for(int rr = 0; rr < 4; rr++){
        long row = rowbase + wr + mi*16 + g4*4 + rr;
        int col = colbase + ni*16 + l16;
        float v = acc[mi][ni][rr];
        v = isK ? (v > 0.f ? v + 1.f : __expf(v)) : v * (1.f / 8192.f);
        dst[row * 256 + col] = f2bf(v);
      }
}

// ---------------------------------------------------------------------------
// kv_acc: per (n, 128-row chunk): partial KV[h][d][v] and Ksum[h][d].
// ---------------------------------------------------------------------------
__global__ __launch_bounds__(256) void kv_acc(const unsigned short* __restrict__ Kw,
                                              const unsigned short* __restrict__ Vw,
                                              float* __restrict__ part){
  const int c = blockIdx.x;      // 0..63
  const int n = blockIdx.y;      // 0..7
  const int t = threadIdx.x;
  const int h = t >> 5, d = t & 31;
  const long base = ((long)n * SEQ + (long)c * 128) * 256;
  float acc[32];
  #pragma unroll
  for(int j = 0; j < 32; j++) acc[j] = 0.f;
  float ks = 0.f;
  for(int rr = 0; rr < 128; rr++){
    const unsigned short* Kr = Kw + base + (long)rr * 256;
    const unsigned short* Vr = Vw + base + (long)rr * 256;
    float kv = bf2f(Kr[h * 32 + d]);
    ks += kv;
    #pragma unroll
    for(int q = 0; q < 4; q++){
      us8 vv = *(const us8*)(Vr + h * 32 + q * 8);
      #pragma unroll
      for(int j = 0; j < 8; j++) acc[q*8 + j] += kv * bf2f(vv[j]);
    }
  }
  float* p = part + ((long)(n * 64 + c) * 33) * 256;
  #pragma unroll
  for(int v = 0; v < 32; v++) p[v * 256 + t] = acc[v];
  p[32 * 256 + t] = ks;
}

// ---------------------------------------------------------------------------
// kv_red: KVws[n][v(33)][t] = sum_c part[n][c][v][t]   (v==32 is Ksum)
// ---------------------------------------------------------------------------
__global__ void kv_red(const float* __restrict__ part, float* __restrict__ KVws){
  const int v = blockIdx.x;   // 0..32
  const int n = blockIdx.y;   // 0..7
  const int t = threadIdx.x;
  float s = 0.f;
  for(int c = 0; c < 64; c++) s += part[((long)(n * 64 + c) * 33 + v) * 256 + t];
  KVws[((long)n * 33 + v) * 256 + t] = s;
}

// ---------------------------------------------------------------------------
// attn: q=xb@Wq -> elu+1 -> att = (Q@KV)*z*S -> msg=att@Wm -> LN1 -> msgln
// grid 1024 (BM=64, BN=256), 256 thr (4 waves, 1x4).
// ---------------------------------------------------------------------------
__global__ __launch_bounds__(256) void attn_kern(
    const unsigned short* __restrict__ xb, const unsigned short* __restrict__ WT,
    const float* __restrict__ KVws, const float* __restrict__ g1,
    const float* __restrict__ b1, unsigned short* __restrict__ msgln)
{
  __shared__ unsigned short As[64][32];     //  4096 B
  __shared__ unsigned short Bu[256][32];    // 16384 B (Wq/Wm chunks, then kvT)
  __shared__ float zs[64][8];               //  2048 B
  __shared__ float ksl[256];                //  1024 B
  __shared__ unsigned short R[64][264];     // 33792 B (Q -> att -> msg)

  const int t = threadIdx.x, lane = t & 63, wid = t >> 6;
  const int l16 = lane & 15, g4 = lane >> 4;
  const int wc = wid * 64;
  const int mb = blockIdx.x;
  const long rowbase = (long)mb * 64;
  const int n = mb >> 7;                    // batch
  const int sr = lane >> 2, sc = (lane & 3) * 8;

  // phase 1: q = xb @ Wq
  f32x4 acc[4][4] = {};
  {
    const unsigned short* wq = WT;          // slot 0
    for(int kb = 0; kb < 256; kb += 32){
      gl16(xb + (rowbase + wid*16 + sr) * 256 + kb + sc, &As[wid*16][0]);
      #pragma unroll
      for(int j = 0; j < 4; j++){
        int r0 = wid * 64 + j * 16;
        gl16(wq + (long)(r0 + sr) * 256 + kb + sc, &Bu[r0][0]);
      }
      __syncthreads();
      short8 afr[4], bfr[4];
      #pragma unroll
      for(int mi = 0; mi < 4; mi++) afr[mi] = *(const short8*)&As[mi*16 + l16][g4*8];
      #pragma unroll
      for(int ni = 0; ni < 4; ni++) bfr[ni] = *(const short8*)&Bu[wc + ni*16 + l16][g4*8];
      #pragma unroll
      for(int mi = 0; mi < 4; mi++)
        #pragma unroll
        for(int ni = 0; ni < 4; ni++)
          acc[mi][ni] = mfma16(afr[mi], bfr[ni], acc[mi][ni]);
      __syncthreads();
    }
  }

  // phase 2: Q = elu(q)+1 -> R (bf16)
  #pragma unroll
  for(int mi = 0; mi < 4; mi++)
    #pragma unroll
    for(int ni = 0; ni < 4; ni++)
      #pragma unroll
      for(int rr = 0; rr < 4; rr++){
        float v = acc[mi][ni][rr];
        v = v > 0.f ? v + 1.f : __expf(v);
        R[mi*16 + g4*4 + rr][wc + ni*16 + l16] = f2bf(v);
      }

  // phase 3: stage kvT (Bu[c=h*32+v][d]) and Ksum
  {
    const float* kvn = KVws + (long)n * 33 * 256;
    const int vv = t & 31, hh = t >> 5;
    #pragma unroll
    for(int d = 0; d < 32; d += 4){
      f32x4 w = *(const f32x4*)(kvn + vv * 256 + hh * 32 + d);
      us4 o; o[0]=f2bf(w[0]); o[1]=f2bf(w[1]); o[2]=f2bf(w[2]); o[3]=f2bf(w[3]);
      *(us4*)&Bu[t][d] = o;
    }
    ksl[t] = kvn[32 * 256 + t];
  }
  __syncthreads();

  // phase 4: z[row][h] = 1/(Q.Ksum + eps)
  #pragma unroll
  for(int pp = 0; pp < 2; pp++){
    int p = t + pp * 256;
    int row = p >> 3, h = p & 7;
    float s = 0.f;
    #pragma unroll
    for(int d = 0; d < 32; d++) s += bf2f(R[row][h*32 + d]) * ksl[h*32 + d];
    zs[row][h] = 1.f / (s + 1e-6f);
  }
  __syncthreads();

  // phase 5: att = (Q @ KV) * z * S
  f32x4 acc2[4][4];
  #pragma unroll
  for(int ni = 0; ni < 4; ni++){
    const int cb = wc + ni * 16;
    const int h = cb >> 5;
    short8 b = *(const short8*)&Bu[cb + l16][g4*8];
    #pragma unroll
    for(int mi = 0; mi < 4; mi++){
      short8 a = *(const short8*)&R[mi*16 + l16][h*32 + g4*8];
      f32x4 zz = {0.f, 0.f, 0.f, 0.f};
      acc2[mi][ni] = mfma16(a, b, zz);
    }
  }
  #pragma unroll
  for(int mi = 0; mi < 4; mi++)
    #pragma unroll
    for(int ni = 0; ni < 4; ni++){
      const int h = (wc + ni * 16) >> 5;
      #pragma unroll
      for(int rr = 0; rr < 4; rr++){
        int row = mi*16 + g4*4 + rr;
        acc2[mi][ni][rr] *= zs[row][h] * 8192.f;
      }
    }
  __syncthreads();   // all R reads done
  #pragma unroll
  for(int mi = 0; mi < 4; mi++)
    #pragma unroll
    for(int ni = 0; ni < 4; ni++)
      #pragma unroll
      for(int rr = 0; rr < 4; rr++)
        R[mi*16 + g4*4 + rr][wc + ni*16 + l16] = f2bf(acc2[mi][ni][rr]);
  __syncthreads();

  // phase 6: msg = att @ Wm
  f32x4 acc3[4][4] = {};
  {
    const unsigned short* wm = WT + 3 * 65536;
    for(int kb = 0; kb < 256; kb += 32){
      #pragma unroll
      for(int j = 0; j < 4; j++){
        int r0 = wid * 64 + j * 16;
        gl16(wm + (long)(r0 + sr) * 256 + kb + sc, &Bu[r0][0]);
      }
      __syncthreads();
      short8 afr[4], bfr[4];
      #pragma unroll
      for(int mi = 0; mi < 4; mi++) afr[mi] = *(const short8*)&R[mi*16 + l16][kb + g4*8];
      #pragma unroll
      for(int ni = 0; ni < 4; ni++) bfr[ni] = *(const short8*)&Bu[wc + ni*16 + l16][g4*8];
      #pragma unroll
      for(int mi = 0; mi < 4; mi++)
        #pragma unroll
        for(int ni = 0; ni < 4; ni++)
          acc3[mi][ni] = mfma16(afr[mi], bfr[ni], acc3[mi][ni]);
      __syncthreads();
    }
  }

  // phase 7: msg -> R
  #pragma unroll
  for(int mi = 0; mi < 4; mi++)
    #pragma unroll
    for(int ni = 0; ni < 4; ni++)
      #pragma unroll
      for(int rr = 0; rr < 4; rr++)
        R[mi*16 + g4*4 + rr][wc + ni*16 + l16] = f2bf(acc3[mi][ni][rr]);
  __syncthreads();

  // phase 8: LN1 + store msgln
  {
    int row = t >> 2, q = t & 3;
    float s = 0.f, ss = 0.f;
    #pragma unroll
    for(int j8 = 0; j8 < 8; j8++){
      us8 vv = *(const us8*)&R[row][q*64 + j8*8];
      #pragma unroll
      for(int e = 0; e < 8; e++){ float v = bf2f(vv[e]); s += v; ss += v * v; }
    }
    s  += __shfl_xor(s, 1);  ss += __shfl_xor(ss, 1);
    s  += __shfl_xor(s, 2);  ss += __shfl_xor(ss, 2);
    float mu  = s * (1.f / 256.f);
    float var = ss * (1.f / 256.f) - mu * mu;
    float rs  = rsqrtf(var + 1e-5f);
    unsigned short* orow = msgln + (rowbase + row) * 256 + q * 64;
    const float* g1p = g1 + q * 64;
    const float* b1p = b1 + q * 64;
    #pragma unroll
    for(int j8 = 0; j8 < 8; j8++){
      us8 vv = *(const us8*)&R[row][q*64 + j8*8];
      us8 o;
      #pragma unroll
      for(int e = 0; e < 8; e++){
        float v = (bf2f(vv[e]) - mu) * rs * g1p[j8*8 + e] + b1p[j8*8 + e];
        o[e] = f2bf(v);
      }
      *(us8*)(orow + j8*8) = o;
    }
  }
}

// ---------------------------------------------------------------------------
// ffn: h = relu(xb@W1a + msgln@W1b); y = h@W2; out = x + LN2(y)
// grid 1024 (BM=64, BN=256), 256 thr.
// ---------------------------------------------------------------------------
__global__ __launch_bounds__(256) void ffn_kern(
    const float* __restrict__ x, const unsigned short* __restrict__ xb,
    const unsigned short* __restrict__ WT,
    const unsigned short* __restrict__ msgln, const float* __restrict__ g2,
    const float* __restrict__ b2, float* __restrict__ out)
{
  __shared__ unsigned short As[64][32];     //  4096 B
  __shared__ unsigned short Bs[256][32];    // 16384 B
  __shared__ unsigned short R[64][264];     // 33792 B
  const int t = threadIdx.x, lane = t & 63, wid = t >> 6;
  const int l16 = lane & 15, g4 = lane >> 4;
  const int wc = wid * 64;
  const long rowbase = (long)blockIdx.x * 64;
  const int sr = lane >> 2, sc = (lane & 3) * 8;

  // phase 1: h = xb@W1a + msgln@W1b  (K_eff = 512)
  f32x4 acc[4][4] = {};
  for(int it = 0; it < 16; it++){
    int kb = (it & 7) * 32;
    const unsigned short* asrc = (it < 8) ? xb : msgln;
    gl16(asrc + (rowbase + wid*16 + sr) * 256 + kb + sc, &As[wid*16][0]);
    const unsigned short* wsl = WT + (it < 8 ? 4 : 5) * 65536;
    #pragma unroll
    for(int j = 0; j < 4; j++){
      int r0 = wid * 64 + j * 16;
      gl16(wsl + (long)(r0 + sr) * 256 + kb + sc, &Bs[r0][0]);
    }
    __syncthreads();
    short8 afr[4], bfr[4];
    #pragma unroll
    for(int mi = 0; mi < 4; mi++) afr[mi] = *(const short8*)&As[mi*16 + l16][g4*8];
    #pragma unroll
    for(int ni = 0; ni < 4; ni++) bfr[ni] = *(const short8*)&Bs[wc + ni*16 + l16][g4*8];
    #pragma unroll
    for(int mi = 0; mi < 4; mi++)
      #pragma unroll
      for(int ni = 0; ni < 4; ni++)
        acc[mi][ni] = mfma16(afr[mi], bfr[ni], acc[mi][ni]);
    __syncthreads();
  }

  // relu -> R
  #pragma unroll
  for(int mi = 0; mi < 4; mi++)
    #pragma unroll
    for(int ni = 0; ni < 4; ni++)
      #pragma unroll
      for(int rr = 0; rr < 4; rr++){
        float v = acc[mi][ni][rr];
        R[mi*16 + g4*4 + rr][wc + ni*16 + l16] = f2bf(v > 0.f ? v : 0.f);
      }
  __syncthreads();

  // phase 2: y = h @ W2
  f32x4 acc2[4][4] = {};
  {
    const unsigned short* w2 = WT + 6 * 65536;
    for(int kb = 0; kb < 256; kb += 32){
      #pragma unroll
      for(int j = 0; j < 4; j++){
        int r0 = wid * 64 + j * 16;
        gl16(w2 + (long)(r0 + sr) * 256 + kb + sc, &Bs[r0][0]);
      }
      __syncthreads();
      short8 afr[4], bfr[4];
      #pragma unroll
      for(int mi = 0; mi < 4; mi++) afr[mi] = *(const short8*)&R[mi*16 + l16][kb + g4*8];
      #pragma unroll
      for(int ni = 0; ni < 4; ni++) bfr[ni] = *(const short8*)&Bs[wc + ni*16 + l16][g4*8];
      #pragma unroll
      for(int mi = 0; mi < 4; mi++)
        #pragma unroll
        for(int ni = 0; ni < 4; ni++)
          acc2[mi][ni] = mfma16(afr[mi], bfr[ni], acc2[mi][ni]);
      __syncthreads();
    }
  }

  // y -> R
  #pragma unroll
  for(int mi = 0; mi < 4; mi++)
    #pragma unroll
    for(int ni = 0; ni < 4; ni++)
      #pragma unroll
      for(int rr = 0; rr < 4; rr++)
        R[mi*16 + g4*4 + rr][wc + ni*16 + l16] = f2bf(acc2[mi][ni][rr]);
  __syncthreads();

  // LN2 + residual + store
  {
    int row = t >> 2, q = t & 3;
    float s = 0.f, ss = 0.f;
    #pragma unroll
    for(int j8 = 0; j8 < 8; j8++){
      us8 vv = *(const us8*)&R[row][q*64 + j8*8];
      #pragma unroll
      for(int e = 0; e < 8; e++){ float v = bf2f(vv[e]); s += v; ss += v * v; }
    }
    s  += __shfl_xor(s, 1);  ss += __shfl_xor(ss, 1);
    s  += __shfl_xor(s, 2);  ss += __shfl_xor(ss, 2);
    float mu  = s * (1.f / 256.f);
    float var = ss * (1.f / 256.f) - mu * mu;
    float rs  = rsqrtf(var + 1e-5f);
    const float* xr = x + (rowbase + row) * 256 + q * 64;
    float* orow = out + (rowbase + row) * 256 + q * 64;
    const float* g2p = g2 + q * 64;
    const float* b2p = b2 + q * 64;
    #pragma unroll
    for(int j4 = 0; j4 < 16; j4++){
      f32x4 xv = *(const f32x4*)(xr + j4 * 4);
      f32x4 o;
      #pragma unroll
      for(int e = 0; e < 4; e++){
        int idx = j4 * 4 + e;
        float v = (bf2f(R[row][q*64 + idx]) - mu) * rs * g2p[idx] + b2p[idx];
        o[e] = xv[e] + v;
      }
      *(f32x4*)(orow + j4 * 4) = o;
    }
  }
}

// ---------------------------------------------------------------------------
extern "C" void kernel_launch(void* const* d_in, const int* in_sizes, int n_in,
                              void* d_out, int out_size, void* d_ws, size_t ws_size,
                              hipStream_t stream)
{
  const float* x   = (const float*)d_in[0];
  const float* src = (const float*)d_in[1];
  const float* Wq  = (const float*)d_in[2];
  const float* Wk  = (const float*)d_in[3];
  const float* Wv  = (const float*)d_in[4];
  const float* Wm  = (const float*)d_in[5];
  const float* W1  = (const float*)d_in[6];
  const float* W2  = (const float*)d_in[7];
  const float* g1  = (const float*)d_in[8];
  const float* b1  = (const float*)d_in[9];
  const float* g2  = (const float*)d_in[10];
  const float* b2  = (const float*)d_in[11];

  char* ws = (char*)d_ws;
  // ws layout (~97.3 MB), region A time-shared by live range:
  //   [0,   1MB)  WT   : 7 x 256 x 256 bf16
  //   [1,  33MB)  A: srcb (conv_src..kv_proj) -> part (kv_acc..kv_red)
  //                  -> xb (conv_x..ffn)    [part = 512*33*256 f32 = 17.3MB]
  //   [33, 65MB)  B: Kw (kv_proj..kv_acc) -> msgln (attn..ffn)
  //   [65, 97MB)  C: Vw (kv_proj..kv_acc)
  //   [97MB, +270336) KVws : 8 x 33 x 256 f32
  unsigned short* WT   = (unsigned short*)(ws);
  unsigned short* srcb = (unsigned short*)(ws + (1ul  << 20));
  float*          part = (float*)         (ws + (1ul  << 20));   // after kv_proj
  unsigned short* xb   = (unsigned short*)(ws + (1ul  << 20));   // after kv_red
  unsigned short* Kw   = (unsigned short*)(ws + (33ul << 20));
  unsigned short* msgl = Kw;                                     // after kv_acc
  unsigned short* Vw   = (unsigned short*)(ws + (65ul << 20));
  float*          KVws = (float*)         (ws + (97ul << 20));

  prep_weights<<<1792, 256, 0, stream>>>(Wq, Wk, Wv, Wm, W1, W2, WT);
  conv_f32_to_bf16<<<2048, 256, 0, stream>>>(src, srcb);
  kv_proj<<<dim3(512, 4), 256, 0, stream>>>(srcb, WT, Kw, Vw);
  kv_acc<<<dim3(64, 8), 256, 0, stream>>>(Kw, Vw, part);
  kv_red<<<dim3(33, 8), 256, 0, stream>>>(part, KVws);
  conv_f32_to_bf16<<<2048, 256, 0, stream>>>(x, xb);
  attn_kern<<<1024, 256, 0, stream>>>(xb, WT, KVws, g1, b1, msgl);
  ffn_kern<<<1024, 256, 0, stream>>>(x, xb, WT, msgl, g2, b2, (float*)d_out);
}